// Round 8
// baseline (202.179 us; speedup 1.0000x reference)
//
#include <hip/hip_runtime.h>
#include <cstdint>
#include <cstddef>

typedef float f4 __attribute__((ext_vector_type(4)));
typedef float f2 __attribute__((ext_vector_type(2)));
typedef float f32x4 __attribute__((ext_vector_type(4)));
typedef short short8 __attribute__((ext_vector_type(8)));
typedef unsigned int u32;
typedef unsigned short u16;
typedef u32 u32x4 __attribute__((ext_vector_type(4)));

// Problem: B=4, H=W=128, CH=64 (G=4 x GC=16), K=3, PAD=1, P=9
// ws layout:
//   vpad  fp32 [4][132][132][64] (2-ring zero) @ 0          17,842,176 B
//   featb bf16 [4][16384][64]                  @ 17,842,176  8,388,608 B
//   x2tp  bf16 [4][130][130][64] swizzled      @ 26,230,784  8,652,800 B
//   wbfT  bf16 [64][576]                       @ 34,883,584     73,728 B
//   whead bf16 [112 cols][64 k]                @ 34,957,312     14,336 B
// (featb A-frag reads overrun <=896B into x2tp on the last rows: valid memory,
//  rows 8..15 of the head MFMA are don't-cares.)

__device__ __forceinline__ u16 f2bf(float f) {
    u32 u = __builtin_bit_cast(u32, f);
    return (u16)((u + 0x7FFFu + ((u >> 16) & 1u)) >> 16);
}

__device__ __forceinline__ int xcd_swz10(int d) {   // 1024 blocks
    return ((d & 7) << 7) | (d >> 3);
}
__device__ __forceinline__ int xcd_swz12(int d) {   // 4096 blocks
    return ((d & 7) << 9) | (d >> 3);
}

// ---------------------------------------------------------------------------
// Kernel A (merged preps): vpad 2-ring zero [0,260) | x2tp ring zero [260,325)
// | w_conv->wbfT [325,397) | wo||wm->whead [397,425)
// ---------------------------------------------------------------------------
__global__ __launch_bounds__(256) void prep_all_k(float* __restrict__ vpad,
                                                  char* __restrict__ x2tp,
                                                  const float* __restrict__ wc,
                                                  const float* __restrict__ wo,
                                                  const float* __restrict__ wm,
                                                  char* __restrict__ wbfT,
                                                  char* __restrict__ whead) {
    int blk = blockIdx.x;
    if (blk < 260) {
        int i = blk * 256 + threadIdx.x;
        if (i >= 66560) return;
        int c4 = i & 15;
        int rest = i >> 4;
        int b = rest / 1040;
        int e = rest - b * 1040;
        int y, x;
        if (e < 132)      { y = 0;   x = e; }
        else if (e < 264) { y = 1;   x = e - 132; }
        else if (e < 396) { y = 130; x = e - 264; }
        else if (e < 528) { y = 131; x = e - 396; }
        else { int e2 = e - 528; y = 2 + (e2 >> 2); int m = e2 & 3;
               x = (m < 2) ? m : m + 128; }
        f4 z = {0.f, 0.f, 0.f, 0.f};
        *(f4*)(vpad + (((size_t)b * 17424 + (size_t)y * 132 + x) * 64 + c4 * 4)) = z;
    } else if (blk < 325) {
        int i = (blk - 260) * 256 + threadIdx.x;
        if (i >= 16512) return;
        int c8 = i & 7;
        int rest = i >> 3;
        int b = rest / 516;
        int e = rest - b * 516;
        int y, x;
        if (e < 130)      { y = 0;       x = e; }
        else if (e < 260) { y = 129;     x = e - 130; }
        else if (e < 388) { y = e - 259; x = 0; }
        else              { y = e - 387; x = 129; }
        u32x4 z = {0u, 0u, 0u, 0u};
        *(u32x4*)(x2tp + ((size_t)b * 16900 + (size_t)y * 130 + x) * 128 + c8 * 16) = z;
    } else if (blk < 397) {
        int i = (blk - 325) * 256 + threadIdx.x;
        int c = i / 288, kp = i - c * 288;
        int k = kp << 1;
        float f0 = wc[(size_t)k * 64 + c];
        float f1 = wc[(size_t)(k + 1) * 64 + c];
        u32 pk = (u32)f2bf(f0) | ((u32)f2bf(f1) << 16);
        *(u32*)(wbfT + (size_t)c * 1152 + kp * 4) = pk;
    } else {
        int i = (blk - 397) * 256 + threadIdx.x;
        int k = i & 63, col = i >> 6;
        float v = 0.f;
        if (col < 72)       v = wo[(size_t)k * 72 + col];
        else if (col < 108) v = wm[(size_t)k * 36 + col - 72];
        *(u16*)(whead + (size_t)(col * 64 + k) * 2) = f2bf(v);
    }
}

// ---------------------------------------------------------------------------
// Kernel C: x2 NCHW fp32 -> x2tp padded NHWC bf16, octet-XOR-swizzled.
// ---------------------------------------------------------------------------
__global__ __launch_bounds__(256) void x2prep_k(const float* __restrict__ x2,
                                                char* __restrict__ x2tp) {
    __shared__ u32 tr[4096];
    int t = threadIdx.x;
    int y = blockIdx.x & 127, b = blockIdx.x >> 7;
    const float* xb = x2 + (size_t)b * 64 * 16384 + (size_t)y * 128;
    #pragma unroll 4
    for (int j = 0; j < 16; j++) {
        int idx = t + (j << 8);
        int x = idx & 127, cip = idx >> 7;
        int ci = cip << 1;
        float f0 = xb[(size_t)ci * 16384 + x];
        float f1 = xb[(size_t)(ci + 1) * 16384 + x];
        u32 pk = (u32)f2bf(f0) | ((u32)f2bf(f1) << 16);
        int key = (x + 1) & 7;
        int byt = x * 128 + (((ci >> 3) ^ key) << 4) + (ci & 7) * 2;
        tr[byt >> 2] = pk;
    }
    __syncthreads();
    const u32x4* src = (const u32x4*)tr;
    u32x4* dst = (u32x4*)(x2tp + ((size_t)(b * 130 + y + 1) * 130 + 1) * 128);
    #pragma unroll
    for (int j = 0; j < 4; j++) {
        int c = t + (j << 8);
        dst[c] = src[c];
    }
}

// ---------------------------------------------------------------------------
// Kernel D: value = x1(NCHW) @ w_value + b_value -> vpad interior (fp32)
// f4-vectorized staging (4 iters/side instead of 16)
// ---------------------------------------------------------------------------
__global__ __launch_bounds__(256) void value_proj_k(const float* __restrict__ x1,
                                                    const float* __restrict__ wv,
                                                    const float* __restrict__ bv,
                                                    float* __restrict__ vpad) {
    __shared__ float xs[64][64];
    __shared__ float wsh[64][64];
    int tid = threadIdx.x;
    int bidx = xcd_swz10(blockIdx.x);
    int xb = bidx & 1;
    int y  = (bidx >> 1) & 127;
    int b  = bidx >> 8;
    int x0 = xb * 64;

    #pragma unroll
    for (int j = 0; j < 4; j++) {
        int chunk = tid + j * 256;           // 1024 f4 chunks
        int ci = chunk >> 4, p4 = chunk & 15;
        *(f4*)&xs[ci][p4 * 4] =
            *(const f4*)(x1 + (((size_t)b * 64 + ci) * 128 + y) * 128 + x0 + p4 * 4);
        *(f4*)&wsh[ci][p4 * 4] = *(const f4*)(wv + ci * 64 + p4 * 4);
    }
    __syncthreads();

    int c0 = (tid & 15) * 4, p0 = (tid >> 4) * 4;
    f4 bb = *(const f4*)(bv + c0);
    f4 acc[4];
    #pragma unroll
    for (int i = 0; i < 4; i++) acc[i] = bb;

    #pragma unroll
    for (int ci = 0; ci < 64; ci++) {
        f4 w4 = *(f4*)&wsh[ci][c0];
        f4 x4 = *(f4*)&xs[ci][p0];
        #pragma unroll
        for (int i = 0; i < 4; i++) acc[i] += x4[i] * w4;
    }

    #pragma unroll
    for (int i = 0; i < 4; i++) {
        int xp = x0 + p0 + i + 2;
        *(f4*)(vpad + (((size_t)b * 132 + (y + 2)) * 132 + xp) * 64 + c0) = acc[i];
    }
}

// ---------------------------------------------------------------------------
// Kernel E: conv3x3 + GELU via bf16 MFMA -> featb (bf16 NHWC)  [unchanged]
// ---------------------------------------------------------------------------
__global__ __launch_bounds__(256, 4) void conv_mfma_k(const char* __restrict__ x2tp,
                                                      const char* __restrict__ wbfT,
                                                      const float* __restrict__ bc,
                                                      char* __restrict__ featb) {
    __shared__ char slab[3 * 8448];
    int tid = threadIdx.x;
    int l = tid & 63, w = tid >> 6;
    int bidx = xcd_swz10(blockIdx.x);
    int xb = bidx & 1, y = (bidx >> 1) & 127, b = bidx >> 8;
    int x0 = xb << 6;

    const char* gr = x2tp + ((size_t)(b * 130 + y) * 130 + x0) * 128;
    for (int q = w; q < 27; q += 4) {
        int r = q / 9, cq = q - r * 9;
        int nb = (cq < 8) ? 1024 : 256;
        if (l * 16 < nb) {
            const char* g = gr + (size_t)r * (130 * 128) + cq * 1024 + l * 16;
            char* p = slab + r * 8448 + cq * 1024 + l * 16;
            __builtin_amdgcn_global_load_lds(
                (const __attribute__((address_space(1))) u32*)g,
                (__attribute__((address_space(3))) u32*)p, 16, 0, 0);
        }
    }
    __syncthreads();

    int m0 = w << 4;
    int r16 = l & 15, g16 = l >> 4;
    f32x4 acc[4] = {{0.f,0.f,0.f,0.f},{0.f,0.f,0.f,0.f},
                    {0.f,0.f,0.f,0.f},{0.f,0.f,0.f,0.f}};
    const char* wb = wbfT + (size_t)r16 * 1152 + g16 * 16;

    #pragma unroll
    for (int s = 0; s < 18; s++) {
        const int t9 = s >> 1;
        const int ky = t9 / 3, kx = t9 - ky * 3;
        const int ci0g = (s & 1) * 4;
        int x_sl = m0 + r16 + kx;
        int go = (ci0g + g16) ^ (x_sl & 7);
        short8 a = *(const short8*)(slab + ky * 8448 + x_sl * 128 + go * 16);
        #pragma unroll
        for (int cb = 0; cb < 4; cb++) {
            short8 bf = *(const short8*)(wb + (size_t)cb * (16 * 1152) + s * 64);
            acc[cb] = __builtin_amdgcn_mfma_f32_16x16x32_bf16(a, bf, acc[cb], 0, 0, 0);
        }
    }

    const float kA = 0.7978845608028654f, kB = 0.044715f;
    char* fp = featb + ((size_t)b * 16384 + (size_t)y * 128 + x0 + m0) * 128;
    #pragma unroll
    for (int cb = 0; cb < 4; cb++) {
        float bcv = bc[cb * 16 + r16];
        #pragma unroll
        for (int j = 0; j < 4; j++) {
            float v = acc[cb][j] + bcv;
            float z = kA * (v + kB * v * v * v);
            float e = __expf(2.f * z);
            float th = 1.f - 2.f / (e + 1.f);
            float o = 0.5f * v * (1.f + th);
            *(u16*)(fp + (size_t)(g16 * 4 + j) * 128 + (cb * 16 + r16) * 2) = f2bf(o);
        }
    }
}

// ---------------------------------------------------------------------------
// Kernel F (v6): v5 with 128-thread blocks (2 waves) for max TLP.
// LDS 11.3 KB/block; __launch_bounds__(128,7) -> ~14 blocks/CU = 28 waves.
// 4096 blocks: b(2) | y(7) | xo(3); wave owns 8 px. 0 barriers.
// ---------------------------------------------------------------------------
__global__ __launch_bounds__(128, 7) void dcn_fused_v6(const char* __restrict__ featb,
                                                       const float* __restrict__ vpad,
                                                       const char* __restrict__ whead,
                                                       const float* __restrict__ bo,
                                                       const float* __restrict__ bm,
                                                       const float* __restrict__ wout,
                                                       const float* __restrict__ bout,
                                                       float* __restrict__ out) {
    __shared__ float off_s [2][8][74];
    __shared__ float msk_s [2][8][38];
    __shared__ float samp_s[2][8][64];

    int tid = threadIdx.x;
    int w = tid >> 6, l = tid & 63;
    int blk = xcd_swz12(blockIdx.x);      // b(2) | y(7) | xo(3)
    int b = blk >> 10, y = (blk >> 3) & 127, xo = blk & 7;
    int x0w = xo * 16 + w * 8;
    int pix0 = ((b << 7) + y) * 128 + x0w;

    int r = l & 15, q = l >> 4;

    // ---- A-frags: 16 rows read, rows 8..15 discarded later (valid memory)
    const char* fpt = featb + (size_t)(pix0 + r) * 128 + q * 16;
    short8 a0 = *(const short8*)fpt;
    short8 a1 = *(const short8*)(fpt + 64);

    // ---- head GEMM: 7 col-tiles x 2 k-steps
    const char* wh = whead + (size_t)r * 128 + q * 16;
    f32x4 hc[7];
    #pragma unroll
    for (int t = 0; t < 7; t++) {
        short8 b0 = *(const short8*)(wh + t * 2048);
        short8 b1 = *(const short8*)(wh + t * 2048 + 64);
        f32x4 z = {0.f, 0.f, 0.f, 0.f};
        z = __builtin_amdgcn_mfma_f32_16x16x32_bf16(a0, b0, z, 0, 0, 0);
        hc[t] = __builtin_amdgcn_mfma_f32_16x16x32_bf16(a1, b1, z, 0, 0, 0);
    }

    // ---- C scatter to LDS (+bias): col = t*16+r, px = q*4+j (keep px<8)
    if (q < 2) {
        #pragma unroll
        for (int t = 0; t < 7; t++) {
            int col = t * 16 + r;
            float bias = 0.f;
            if (col < 72)        bias = bo[col];
            else if (col < 108)  bias = bm[col - 72];
            #pragma unroll
            for (int j = 0; j < 4; j++) {
                int px = q * 4 + j;
                float v = hc[t][j] + bias;
                if (col < 72)       off_s[w][px][col] = v;
                else if (col < 108) msk_s[w][px][col - 72] = v;
            }
        }
    }

    // ---- softmax: lanes 0..31 -> (px = l>>2, g = l&3), fully parallel
    if (l < 32) {
        int px = l >> 2, g = l & 3;
        float m[9];
        #pragma unroll
        for (int p = 0; p < 9; p++) m[p] = msk_s[w][px][g * 9 + p];
        float mx = m[0];
        #pragma unroll
        for (int p = 1; p < 9; p++) mx = fmaxf(mx, m[p]);
        float s = 0.f;
        #pragma unroll
        for (int p = 0; p < 9; p++) { m[p] = __expf(m[p] - mx); s += m[p]; }
        float inv = 1.f / s;
        #pragma unroll
        for (int p = 0; p < 9; p++) msk_s[w][px][g * 9 + p] = m[p] * inv;
    }

    // ---- sampling: lane = (cc4 = l&3, g = (l>>2)&3, pxs = l>>4); 2 px / lane
    {
        int cc4 = l & 3, g = (l >> 2) & 3, pxs = l >> 4;
        const float* vb = vpad + (size_t)b * 17424 * 64 + g * 16 + cc4 * 4;
        #pragma unroll
        for (int j = 0; j < 2; j++) {
            int px = pxs * 2 + j;
            int xpix = x0w + px;
            f4 acc = {0.f, 0.f, 0.f, 0.f};
            #pragma unroll
            for (int p = 0; p < 9; p++) {
                const int kx = p % 3, ky = p / 3;
                f2 oxy = *(const f2*)&off_s[w][px][g * 18 + 2 * p];
                float mv = msk_s[w][px][g * 9 + p];
                float sx = (float)(xpix + kx) + oxy[0];
                float sy = (float)(y + ky) + oxy[1];
                float xf = floorf(sx), yf = floorf(sy);
                float fx = sx - xf, fy = sy - yf;
                int ix = (int)xf, iy = (int)yf;           // in [-1,129]
                int e0 = (iy * 132 + ix + 133) << 6;
                const float* pa = vb + e0;
                f4 v00 = *(const f4*)pa;
                f4 v01 = *(const f4*)(pa + 64);
                f4 v10 = *(const f4*)(pa + 8448);
                f4 v11 = *(const f4*)(pa + 8512);
                float wy0 = mv * (1.f - fy), wy1 = mv * fy;
                float w00 = wy0 * (1.f - fx), w01 = wy0 * fx;
                float w10 = wy1 * (1.f - fx), w11 = wy1 * fx;
                #pragma unroll
                for (int c = 0; c < 4; c++)
                    acc[c] = fmaf(w00, v00[c],
                             fmaf(w01, v01[c],
                             fmaf(w10, v10[c],
                             fmaf(w11, v11[c], acc[c]))));
            }
            *(f4*)&samp_s[w][px][g * 16 + cc4 * 4] = acc;
        }
    }

    // ---- out projection (fp32): lane = out-ch, 8 px batched
    float oa[8];
    float bv = bout[l];
    #pragma unroll
    for (int px = 0; px < 8; px++) oa[px] = bv;
    const float* pw = wout + l;
    #pragma unroll 4
    for (int k4 = 0; k4 < 16; k4++) {
        float w0 = pw[0], w1 = pw[64], w2 = pw[128], w3 = pw[192];
        pw += 256;
        #pragma unroll
        for (int px = 0; px < 8; px++) {
            f4 sv = *(f4*)&samp_s[w][px][k4 * 4];
            oa[px] = fmaf(sv[0], w0, fmaf(sv[1], w1,
                     fmaf(sv[2], w2, fmaf(sv[3], w3, oa[px]))));
        }
    }

    // ---- NCHW store: lane = channel, 8 consecutive x (32 B/lane)
    float* op = out + ((size_t)b * 64 + l) * 16384 + y * 128 + x0w;
    f4 o0 = {oa[0], oa[1], oa[2], oa[3]};
    f4 o1 = {oa[4], oa[5], oa[6], oa[7]};
    *(f4*)op       = o0;
    *(f4*)(op + 4) = o1;
}

// ---------------------------------------------------------------------------
extern "C" void kernel_launch(void* const* d_in, const int* in_sizes, int n_in,
                              void* d_out, int out_size, void* d_ws, size_t ws_size,
                              hipStream_t stream) {
    const float* x1       = (const float*)d_in[0];
    const float* x2       = (const float*)d_in[1];
    const float* w_value  = (const float*)d_in[2];
    const float* b_value  = (const float*)d_in[3];
    const float* w_conv   = (const float*)d_in[4];
    const float* b_conv   = (const float*)d_in[5];
    const float* w_offset = (const float*)d_in[6];
    const float* b_offset = (const float*)d_in[7];
    const float* w_mask   = (const float*)d_in[8];
    const float* b_mask   = (const float*)d_in[9];
    const float* w_out    = (const float*)d_in[10];
    const float* b_out    = (const float*)d_in[11];

    float* vpad  = (float*)d_ws;
    char*  featb = (char*)d_ws + 17842176;
    char*  x2tp  = (char*)d_ws + 26230784;
    char*  wbfT  = (char*)d_ws + 34883584;
    char*  whead = (char*)d_ws + 34957312;
    float* outp  = (float*)d_out;

    hipLaunchKernelGGL(prep_all_k,   dim3(425),  dim3(256), 0, stream,
                       vpad, x2tp, w_conv, w_offset, w_mask, wbfT, whead);
    hipLaunchKernelGGL(x2prep_k,     dim3(512),  dim3(256), 0, stream, x2, x2tp);
    hipLaunchKernelGGL(value_proj_k, dim3(1024), dim3(256), 0, stream,
                       x1, w_value, b_value, vpad);
    hipLaunchKernelGGL(conv_mfma_k,  dim3(1024), dim3(256), 0, stream,
                       x2tp, wbfT, b_conv, featb);
    hipLaunchKernelGGL(dcn_fused_v6, dim3(4096), dim3(128), 0, stream,
                       featb, vpad, whead, b_offset, b_mask, w_out, b_out, outp);
}

// Round 9
// 199.753 us; speedup vs baseline: 1.0121x; 1.0121x over previous
//
#include <hip/hip_runtime.h>
#include <cstdint>
#include <cstddef>

typedef float f4 __attribute__((ext_vector_type(4)));
typedef float f2 __attribute__((ext_vector_type(2)));
typedef float f32x4 __attribute__((ext_vector_type(4)));
typedef short short8 __attribute__((ext_vector_type(8)));
typedef unsigned int u32;
typedef unsigned short u16;
typedef u32 u32x2 __attribute__((ext_vector_type(2)));
typedef u32 u32x4 __attribute__((ext_vector_type(4)));

// Problem: B=4, H=W=128, CH=64 (G=4 x GC=16), K=3, PAD=1, P=9
// ws layout:
//   vpad  fp32 [4][132][132][64] (2-ring zero) @ 0          17,842,176 B
//   featb bf16 [4][16384][64]                  @ 17,842,176  8,388,608 B
//   x2tp  bf16 [4][130][130][64] swizzled      @ 26,230,784  8,652,800 B
//   wbfT  bf16 [64][576]                       @ 34,883,584     73,728 B
//   whead bf16 [112 cols][64 k]                @ 34,957,312     14,336 B

__device__ __forceinline__ u16 f2bf(float f) {
    u32 u = __builtin_bit_cast(u32, f);
    return (u16)((u + 0x7FFFu + ((u >> 16) & 1u)) >> 16);
}

__device__ __forceinline__ int xcd_swz10(int d) {   // 1024 blocks
    return ((d & 7) << 7) | (d >> 3);
}
__device__ __forceinline__ int xcd_swz11(int d) {   // 2048 blocks
    return ((d & 7) << 8) | (d >> 3);
}

// ---------------------------------------------------------------------------
// Kernel A (merged preps): vpad 2-ring zero [0,260) | x2tp ring zero [260,325)
// | w_conv->wbfT [325,397) | wo||wm->whead [397,425)
// ---------------------------------------------------------------------------
__global__ __launch_bounds__(256) void prep_all_k(float* __restrict__ vpad,
                                                  char* __restrict__ x2tp,
                                                  const float* __restrict__ wc,
                                                  const float* __restrict__ wo,
                                                  const float* __restrict__ wm,
                                                  char* __restrict__ wbfT,
                                                  char* __restrict__ whead) {
    int blk = blockIdx.x;
    if (blk < 260) {
        int i = blk * 256 + threadIdx.x;
        if (i >= 66560) return;
        int c4 = i & 15;
        int rest = i >> 4;
        int b = rest / 1040;
        int e = rest - b * 1040;
        int y, x;
        if (e < 132)      { y = 0;   x = e; }
        else if (e < 264) { y = 1;   x = e - 132; }
        else if (e < 396) { y = 130; x = e - 264; }
        else if (e < 528) { y = 131; x = e - 396; }
        else { int e2 = e - 528; y = 2 + (e2 >> 2); int m = e2 & 3;
               x = (m < 2) ? m : m + 128; }
        f4 z = {0.f, 0.f, 0.f, 0.f};
        *(f4*)(vpad + (((size_t)b * 17424 + (size_t)y * 132 + x) * 64 + c4 * 4)) = z;
    } else if (blk < 325) {
        int i = (blk - 260) * 256 + threadIdx.x;
        if (i >= 16512) return;
        int c8 = i & 7;
        int rest = i >> 3;
        int b = rest / 516;
        int e = rest - b * 516;
        int y, x;
        if (e < 130)      { y = 0;       x = e; }
        else if (e < 260) { y = 129;     x = e - 130; }
        else if (e < 388) { y = e - 259; x = 0; }
        else              { y = e - 387; x = 129; }
        u32x4 z = {0u, 0u, 0u, 0u};
        *(u32x4*)(x2tp + ((size_t)b * 16900 + (size_t)y * 130 + x) * 128 + c8 * 16) = z;
    } else if (blk < 397) {
        int i = (blk - 325) * 256 + threadIdx.x;
        int c = i / 288, kp = i - c * 288;
        int k = kp << 1;
        float f0 = wc[(size_t)k * 64 + c];
        float f1 = wc[(size_t)(k + 1) * 64 + c];
        u32 pk = (u32)f2bf(f0) | ((u32)f2bf(f1) << 16);
        *(u32*)(wbfT + (size_t)c * 1152 + kp * 4) = pk;
    } else {
        int i = (blk - 397) * 256 + threadIdx.x;
        int k = i & 63, col = i >> 6;
        float v = 0.f;
        if (col < 72)       v = wo[(size_t)k * 72 + col];
        else if (col < 108) v = wm[(size_t)k * 36 + col - 72];
        *(u16*)(whead + (size_t)(col * 64 + k) * 2) = f2bf(v);
    }
}

// ---------------------------------------------------------------------------
// Kernel C: x2 NCHW fp32 -> x2tp padded NHWC bf16, octet-XOR-swizzled.
// ---------------------------------------------------------------------------
__global__ __launch_bounds__(256) void x2prep_k(const float* __restrict__ x2,
                                                char* __restrict__ x2tp) {
    __shared__ u32 tr[4096];
    int t = threadIdx.x;
    int y = blockIdx.x & 127, b = blockIdx.x >> 7;
    const float* xb = x2 + (size_t)b * 64 * 16384 + (size_t)y * 128;
    #pragma unroll 4
    for (int j = 0; j < 16; j++) {
        int idx = t + (j << 8);
        int x = idx & 127, cip = idx >> 7;
        int ci = cip << 1;
        float f0 = xb[(size_t)ci * 16384 + x];
        float f1 = xb[(size_t)(ci + 1) * 16384 + x];
        u32 pk = (u32)f2bf(f0) | ((u32)f2bf(f1) << 16);
        int key = (x + 1) & 7;
        int byt = x * 128 + (((ci >> 3) ^ key) << 4) + (ci & 7) * 2;
        tr[byt >> 2] = pk;
    }
    __syncthreads();
    const u32x4* src = (const u32x4*)tr;
    u32x4* dst = (u32x4*)(x2tp + ((size_t)(b * 130 + y + 1) * 130 + 1) * 128);
    #pragma unroll
    for (int j = 0; j < 4; j++) {
        int c = t + (j << 8);
        dst[c] = src[c];
    }
}

// ---------------------------------------------------------------------------
// Kernel D: value = x1(NCHW) @ w_value + b_value -> vpad interior (fp32)
// ---------------------------------------------------------------------------
__global__ __launch_bounds__(256) void value_proj_k(const float* __restrict__ x1,
                                                    const float* __restrict__ wv,
                                                    const float* __restrict__ bv,
                                                    float* __restrict__ vpad) {
    __shared__ float xs[64][64];
    __shared__ float wsh[64][64];
    int tid = threadIdx.x;
    int bidx = xcd_swz10(blockIdx.x);
    int xb = bidx & 1;
    int y  = (bidx >> 1) & 127;
    int b  = bidx >> 8;
    int x0 = xb * 64;

    #pragma unroll
    for (int j = 0; j < 4; j++) {
        int chunk = tid + j * 256;
        int ci = chunk >> 4, p4 = chunk & 15;
        *(f4*)&xs[ci][p4 * 4] =
            *(const f4*)(x1 + (((size_t)b * 64 + ci) * 128 + y) * 128 + x0 + p4 * 4);
        *(f4*)&wsh[ci][p4 * 4] = *(const f4*)(wv + ci * 64 + p4 * 4);
    }
    __syncthreads();

    int c0 = (tid & 15) * 4, p0 = (tid >> 4) * 4;
    f4 bb = *(const f4*)(bv + c0);
    f4 acc[4];
    #pragma unroll
    for (int i = 0; i < 4; i++) acc[i] = bb;

    #pragma unroll
    for (int ci = 0; ci < 64; ci++) {
        f4 w4 = *(f4*)&wsh[ci][c0];
        f4 x4 = *(f4*)&xs[ci][p0];
        #pragma unroll
        for (int i = 0; i < 4; i++) acc[i] += x4[i] * w4;
    }

    #pragma unroll
    for (int i = 0; i < 4; i++) {
        int xp = x0 + p0 + i + 2;
        *(f4*)(vpad + (((size_t)b * 132 + (y + 2)) * 132 + xp) * 64 + c0) = acc[i];
    }
}

// ---------------------------------------------------------------------------
// Kernel E (v2): conv3x3 + GELU, bf16 MFMA, retiled 32px/2-wave/2048-block
// (8 blocks/CU vs old 4). Operands SWAPPED (A=weights, B=pixels): identical
// frag addresses by layout symmetry; D[row=ch][col=px] gives each lane 4
// consecutive channels -> dwordx2 bf16 stores (was 16 short-stores).
// ---------------------------------------------------------------------------
__global__ __launch_bounds__(128, 4) void conv_mfma_k(const char* __restrict__ x2tp,
                                                      const char* __restrict__ wbfT,
                                                      const float* __restrict__ bc,
                                                      char* __restrict__ featb) {
    __shared__ char slab[3 * 4352];            // 3 rows x 34 px x 128 B
    int tid = threadIdx.x;
    int l = tid & 63, w = tid >> 6;
    int bidx = xcd_swz11(blockIdx.x);          // b(2) | y(7) | xq(2)
    int xq = bidx & 3, y = (bidx >> 2) & 127, b = bidx >> 9;
    int x0 = xq << 5;

    // stage rows y..y+2 (padded), px x0..x0+33; LDS dest linear in q
    const char* gr = x2tp + ((size_t)(b * 130 + y) * 130 + x0) * 128;
    for (int q = tid; q < 816; q += 128) {
        int r = q / 272, c = q - r * 272;
        const char* g = gr + (size_t)r * (130 * 128) + c * 16;
        char* p = slab + q * 16;
        __builtin_amdgcn_global_load_lds(
            (const __attribute__((address_space(1))) u32*)g,
            (__attribute__((address_space(3))) u32*)p, 16, 0, 0);
    }
    __syncthreads();

    int m0 = w << 4;                           // wave px offset: 0 or 16
    int r16 = l & 15, g16 = l >> 4;
    f32x4 acc[4] = {{0.f,0.f,0.f,0.f},{0.f,0.f,0.f,0.f},
                    {0.f,0.f,0.f,0.f},{0.f,0.f,0.f,0.f}};
    const char* wb = wbfT + (size_t)r16 * 1152 + g16 * 16;

    #pragma unroll
    for (int s = 0; s < 18; s++) {
        const int t9 = s >> 1;
        const int ky = t9 / 3, kx = t9 - ky * 3;
        const int ci0g = (s & 1) * 4;
        int x_sl = m0 + r16 + kx;              // 0..33; x0%8==0 so key=x_sl&7
        int go = (ci0g + g16) ^ (x_sl & 7);
        short8 a = *(const short8*)(slab + ky * 4352 + x_sl * 128 + go * 16);
        #pragma unroll
        for (int cb = 0; cb < 4; cb++) {
            short8 bf = *(const short8*)(wb + (size_t)cb * (16 * 1152) + s * 64);
            // swapped: A = weights (row=ch), B = pixels (col=px)
            acc[cb] = __builtin_amdgcn_mfma_f32_16x16x32_bf16(bf, a, acc[cb], 0, 0, 0);
        }
    }

    // epilogue: lane owns px = x0+m0+r16, ch = cb*16 + g16*4 + j
    const float kA = 0.7978845608028654f, kB = 0.044715f;
    char* fp = featb + ((size_t)b * 16384 + (size_t)y * 128 + x0 + m0 + r16) * 128;
    #pragma unroll
    for (int cb = 0; cb < 4; cb++) {
        f4 b4 = *(const f4*)(bc + cb * 16 + g16 * 4);
        u16 h[4];
        #pragma unroll
        for (int j = 0; j < 4; j++) {
            float v = acc[cb][j] + b4[j];
            float z = kA * (v + kB * v * v * v);
            float e = __expf(2.f * z);
            float th = 1.f - 2.f / (e + 1.f);
            h[j] = f2bf(0.5f * v * (1.f + th));
        }
        u32x2 pk = {(u32)h[0] | ((u32)h[1] << 16), (u32)h[2] | ((u32)h[3] << 16)};
        *(u32x2*)(fp + cb * 32 + g16 * 8) = pk;
    }
}

// ---------------------------------------------------------------------------
// Kernel F (v5r): measured-best dcn config (R7: 56us). 2048 blocks, 256 thr,
// 4 waves x 8px, wave-private LDS, 0 barriers. + featb rows read as (r&7)
// so the 16-row A-frag only touches the 8 owned pixels.
// ---------------------------------------------------------------------------
__global__ __launch_bounds__(256, 6) void dcn_fused_v5(const char* __restrict__ featb,
                                                       const float* __restrict__ vpad,
                                                       const char* __restrict__ whead,
                                                       const float* __restrict__ bo,
                                                       const float* __restrict__ bm,
                                                       const float* __restrict__ wout,
                                                       const float* __restrict__ bout,
                                                       float* __restrict__ out) {
    __shared__ float off_s [4][8][74];
    __shared__ float msk_s [4][8][38];
    __shared__ float samp_s[4][8][64];

    int tid = threadIdx.x;
    int w = tid >> 6, l = tid & 63;
    int blk = xcd_swz11(blockIdx.x);      // b(2) | y(7) | xq(2)
    int b = blk >> 9, y = (blk >> 2) & 127, xq = blk & 3;
    int x0w = xq * 32 + w * 8;
    int pix0 = ((b << 7) + y) * 128 + x0w;

    int r = l & 15, q = l >> 4;

    // ---- A-frags: row (r&7) -> only the 8 owned px touched (rows 8..15 dup)
    const char* fpt = featb + (size_t)(pix0 + (r & 7)) * 128 + q * 16;
    short8 a0 = *(const short8*)fpt;
    short8 a1 = *(const short8*)(fpt + 64);

    // ---- head GEMM: 7 col-tiles x 2 k-steps
    const char* wh = whead + (size_t)r * 128 + q * 16;
    f32x4 hc[7];
    #pragma unroll
    for (int t = 0; t < 7; t++) {
        short8 b0 = *(const short8*)(wh + t * 2048);
        short8 b1 = *(const short8*)(wh + t * 2048 + 64);
        f32x4 z = {0.f, 0.f, 0.f, 0.f};
        z = __builtin_amdgcn_mfma_f32_16x16x32_bf16(a0, b0, z, 0, 0, 0);
        hc[t] = __builtin_amdgcn_mfma_f32_16x16x32_bf16(a1, b1, z, 0, 0, 0);
    }

    // ---- C scatter to LDS (+bias): col = t*16+r, px = q*4+j (keep px<8)
    if (q < 2) {
        #pragma unroll
        for (int t = 0; t < 7; t++) {
            int col = t * 16 + r;
            float bias = 0.f;
            if (col < 72)        bias = bo[col];
            else if (col < 108)  bias = bm[col - 72];
            #pragma unroll
            for (int j = 0; j < 4; j++) {
                int px = q * 4 + j;
                float v = hc[t][j] + bias;
                if (col < 72)       off_s[w][px][col] = v;
                else if (col < 108) msk_s[w][px][col - 72] = v;
            }
        }
    }

    // ---- softmax: lanes 0..31 -> (px = l>>2, g = l&3), fully parallel
    if (l < 32) {
        int px = l >> 2, g = l & 3;
        float m[9];
        #pragma unroll
        for (int p = 0; p < 9; p++) m[p] = msk_s[w][px][g * 9 + p];
        float mx = m[0];
        #pragma unroll
        for (int p = 1; p < 9; p++) mx = fmaxf(mx, m[p]);
        float s = 0.f;
        #pragma unroll
        for (int p = 0; p < 9; p++) { m[p] = __expf(m[p] - mx); s += m[p]; }
        float inv = 1.f / s;
        #pragma unroll
        for (int p = 0; p < 9; p++) msk_s[w][px][g * 9 + p] = m[p] * inv;
    }

    // ---- sampling: lane = (cc4 = l&3, g = (l>>2)&3, pxs = l>>4); 2 px / lane
    {
        int cc4 = l & 3, g = (l >> 2) & 3, pxs = l >> 4;
        const float* vb = vpad + (size_t)b * 17424 * 64 + g * 16 + cc4 * 4;
        #pragma unroll
        for (int j = 0; j < 2; j++) {
            int px = pxs * 2 + j;
            int xpix = x0w + px;
            f4 acc = {0.f, 0.f, 0.f, 0.f};
            #pragma unroll
            for (int p = 0; p < 9; p++) {
                const int kx = p % 3, ky = p / 3;
                f2 oxy = *(const f2*)&off_s[w][px][g * 18 + 2 * p];
                float mv = msk_s[w][px][g * 9 + p];
                float sx = (float)(xpix + kx) + oxy[0];
                float sy = (float)(y + ky) + oxy[1];
                float xf = floorf(sx), yf = floorf(sy);
                float fx = sx - xf, fy = sy - yf;
                int ix = (int)xf, iy = (int)yf;           // in [-1,129]
                int e0 = (iy * 132 + ix + 133) << 6;
                const float* pa = vb + e0;
                f4 v00 = *(const f4*)pa;
                f4 v01 = *(const f4*)(pa + 64);
                f4 v10 = *(const f4*)(pa + 8448);
                f4 v11 = *(const f4*)(pa + 8512);
                float wy0 = mv * (1.f - fy), wy1 = mv * fy;
                float w00 = wy0 * (1.f - fx), w01 = wy0 * fx;
                float w10 = wy1 * (1.f - fx), w11 = wy1 * fx;
                #pragma unroll
                for (int c = 0; c < 4; c++)
                    acc[c] = fmaf(w00, v00[c],
                             fmaf(w01, v01[c],
                             fmaf(w10, v10[c],
                             fmaf(w11, v11[c], acc[c]))));
            }
            *(f4*)&samp_s[w][px][g * 16 + cc4 * 4] = acc;
        }
    }

    // ---- out projection (fp32): lane = out-ch, 8 px batched
    float oa[8];
    float bv = bout[l];
    #pragma unroll
    for (int px = 0; px < 8; px++) oa[px] = bv;
    const float* pw = wout + l;
    #pragma unroll 4
    for (int k4 = 0; k4 < 16; k4++) {
        float w0 = pw[0], w1 = pw[64], w2 = pw[128], w3 = pw[192];
        pw += 256;
        #pragma unroll
        for (int px = 0; px < 8; px++) {
            f4 sv = *(f4*)&samp_s[w][px][k4 * 4];
            oa[px] = fmaf(sv[0], w0, fmaf(sv[1], w1,
                     fmaf(sv[2], w2, fmaf(sv[3], w3, oa[px]))));
        }
    }

    // ---- NCHW store: lane = channel, 8 consecutive x (32 B/lane; the 4
    // waves of the block cover 32 contiguous x -> full-line merge in L2)
    float* op = out + ((size_t)b * 64 + l) * 16384 + y * 128 + x0w;
    f4 o0 = {oa[0], oa[1], oa[2], oa[3]};
    f4 o1 = {oa[4], oa[5], oa[6], oa[7]};
    *(f4*)op       = o0;
    *(f4*)(op + 4) = o1;
}

// ---------------------------------------------------------------------------
extern "C" void kernel_launch(void* const* d_in, const int* in_sizes, int n_in,
                              void* d_out, int out_size, void* d_ws, size_t ws_size,
                              hipStream_t stream) {
    const float* x1       = (const float*)d_in[0];
    const float* x2       = (const float*)d_in[1];
    const float* w_value  = (const float*)d_in[2];
    const float* b_value  = (const float*)d_in[3];
    const float* w_conv   = (const float*)d_in[4];
    const float* b_conv   = (const float*)d_in[5];
    const float* w_offset = (const float*)d_in[6];
    const float* b_offset = (const float*)d_in[7];
    const float* w_mask   = (const float*)d_in[8];
    const float* b_mask   = (const float*)d_in[9];
    const float* w_out    = (const float*)d_in[10];
    const float* b_out    = (const float*)d_in[11];

    float* vpad  = (float*)d_ws;
    char*  featb = (char*)d_ws + 17842176;
    char*  x2tp  = (char*)d_ws + 26230784;
    char*  wbfT  = (char*)d_ws + 34883584;
    char*  whead = (char*)d_ws + 34957312;
    float* outp  = (float*)d_out;

    hipLaunchKernelGGL(prep_all_k,   dim3(425),  dim3(256), 0, stream,
                       vpad, x2tp, w_conv, w_offset, w_mask, wbfT, whead);
    hipLaunchKernelGGL(x2prep_k,     dim3(512),  dim3(256), 0, stream, x2, x2tp);
    hipLaunchKernelGGL(value_proj_k, dim3(1024), dim3(256), 0, stream,
                       x1, w_value, b_value, vpad);
    hipLaunchKernelGGL(conv_mfma_k,  dim3(2048), dim3(128), 0, stream,
                       x2tp, wbfT, b_conv, featb);
    hipLaunchKernelGGL(dcn_fused_v5, dim3(2048), dim3(256), 0, stream,
                       featb, vpad, whead, b_offset, b_mask, w_out, b_out, outp);
}

// Round 11
// 192.155 us; speedup vs baseline: 1.0522x; 1.0395x over previous
//
#include <hip/hip_runtime.h>
#include <cstdint>
#include <cstddef>

typedef float f4 __attribute__((ext_vector_type(4)));
typedef float f2 __attribute__((ext_vector_type(2)));
typedef float f32x4 __attribute__((ext_vector_type(4)));
typedef short short8 __attribute__((ext_vector_type(8)));
typedef unsigned int u32;
typedef unsigned short u16;
typedef u32 u32x2 __attribute__((ext_vector_type(2)));
typedef u32 u32x4 __attribute__((ext_vector_type(4)));

// Problem: B=4, H=W=128, CH=64 (G=4 x GC=16), K=3, PAD=1, P=9
// ws layout (R9-identical):
//   vpad  fp32 [4][132][132][64] (2-ring zero) @ 0          17,842,176 B
//   featb bf16 [4][16384][64]                  @ 17,842,176  8,388,608 B
//   x2tp  bf16 [4][130][130][64] swizzled      @ 26,230,784  8,652,800 B
//   wbfT  bf16 [64][576]                       @ 34,883,584     73,728 B
//   whead bf16 [112 cols][64 k]                @ 34,957,312     14,336 B
// Pipeline: 3 launches. Mega-kernel = GRID-level fusion of the three
// independent R9 bodies (verbatim code, disjoint writes); conv + dcn verbatim.

__device__ __forceinline__ u16 f2bf(float f) {
    u32 u = __builtin_bit_cast(u32, f);
    return (u16)((u + 0x7FFFu + ((u >> 16) & 1u)) >> 16);
}

__device__ __forceinline__ int xcd_swz10(int d) {   // 1024 blocks
    return ((d & 7) << 7) | (d >> 3);
}
__device__ __forceinline__ int xcd_swz11(int d) {   // 2048 blocks
    return ((d & 7) << 8) | (d >> 3);
}

// ---------------------------------------------------------------------------
// Kernel 1 (mega): blocks [0,425) = prep_all | [425,937) = x2prep |
// [937,1961) = value_proj. Each body verbatim from R9; 32 KB LDS union.
// ---------------------------------------------------------------------------
__global__ __launch_bounds__(256, 4) void mega_prep_k(float* __restrict__ vpad,
                                                      char* __restrict__ x2tp,
                                                      const float* __restrict__ wc,
                                                      const float* __restrict__ wo,
                                                      const float* __restrict__ wm,
                                                      char* __restrict__ wbfT,
                                                      char* __restrict__ whead,
                                                      const float* __restrict__ x2,
                                                      const float* __restrict__ x1,
                                                      const float* __restrict__ wv,
                                                      const float* __restrict__ bv) {
    __shared__ __align__(16) char smem[32768];
    int blk = blockIdx.x;

    if (blk < 425) {
        // ===== prep_all body (R8/R9 verbatim; no LDS) =====
        if (blk < 260) {
            int i = blk * 256 + threadIdx.x;
            if (i >= 66560) return;
            int c4 = i & 15;
            int rest = i >> 4;
            int b = rest / 1040;
            int e = rest - b * 1040;
            int y, x;
            if (e < 132)      { y = 0;   x = e; }
            else if (e < 264) { y = 1;   x = e - 132; }
            else if (e < 396) { y = 130; x = e - 264; }
            else if (e < 528) { y = 131; x = e - 396; }
            else { int e2 = e - 528; y = 2 + (e2 >> 2); int m = e2 & 3;
                   x = (m < 2) ? m : m + 128; }
            f4 z = {0.f, 0.f, 0.f, 0.f};
            *(f4*)(vpad + (((size_t)b * 17424 + (size_t)y * 132 + x) * 64 + c4 * 4)) = z;
        } else if (blk < 325) {
            int i = (blk - 260) * 256 + threadIdx.x;
            if (i >= 16512) return;
            int c8 = i & 7;
            int rest = i >> 3;
            int b = rest / 516;
            int e = rest - b * 516;
            int y, x;
            if (e < 130)      { y = 0;       x = e; }
            else if (e < 260) { y = 129;     x = e - 130; }
            else if (e < 388) { y = e - 259; x = 0; }
            else              { y = e - 387; x = 129; }
            u32x4 z = {0u, 0u, 0u, 0u};
            *(u32x4*)(x2tp + ((size_t)b * 16900 + (size_t)y * 130 + x) * 128 + c8 * 16) = z;
        } else if (blk < 397) {
            int i = (blk - 325) * 256 + threadIdx.x;
            int c = i / 288, kp = i - c * 288;
            int k = kp << 1;
            float f0 = wc[(size_t)k * 64 + c];
            float f1 = wc[(size_t)(k + 1) * 64 + c];
            u32 pk = (u32)f2bf(f0) | ((u32)f2bf(f1) << 16);
            *(u32*)(wbfT + (size_t)c * 1152 + kp * 4) = pk;
        } else {
            int i = (blk - 397) * 256 + threadIdx.x;
            int k = i & 63, col = i >> 6;
            float v = 0.f;
            if (col < 72)       v = wo[(size_t)k * 72 + col];
            else if (col < 108) v = wm[(size_t)k * 36 + col - 72];
            *(u16*)(whead + (size_t)(col * 64 + k) * 2) = f2bf(v);
        }
    } else if (blk < 937) {
        // ===== x2prep body (R9 verbatim; tr = 16 KB of smem) =====
        u32* tr = (u32*)smem;
        int local = blk - 425;
        int t = threadIdx.x;
        int y = local & 127, b = local >> 7;
        const float* xb = x2 + (size_t)b * 64 * 16384 + (size_t)y * 128;
        #pragma unroll 4
        for (int j = 0; j < 16; j++) {
            int idx = t + (j << 8);
            int x = idx & 127, cip = idx >> 7;
            int ci = cip << 1;
            float f0 = xb[(size_t)ci * 16384 + x];
            float f1 = xb[(size_t)(ci + 1) * 16384 + x];
            u32 pk = (u32)f2bf(f0) | ((u32)f2bf(f1) << 16);
            int key = (x + 1) & 7;
            int byt = x * 128 + (((ci >> 3) ^ key) << 4) + (ci & 7) * 2;
            tr[byt >> 2] = pk;
        }
        __syncthreads();
        const u32x4* src = (const u32x4*)tr;
        u32x4* dst = (u32x4*)(x2tp + ((size_t)(b * 130 + y + 1) * 130 + 1) * 128);
        #pragma unroll
        for (int j = 0; j < 4; j++) {
            int c = t + (j << 8);
            dst[c] = src[c];
        }
    } else {
        // ===== value_proj body (R9 verbatim; xs/wsh overlay smem) =====
        float (*xs)[64]  = (float(*)[64])smem;
        float (*wsh)[64] = (float(*)[64])(smem + 16384);
        int tid = threadIdx.x;
        int bidx = xcd_swz10(blk - 937);
        int xb = bidx & 1;
        int y  = (bidx >> 1) & 127;
        int b  = bidx >> 8;
        int x0 = xb * 64;

        #pragma unroll
        for (int j = 0; j < 4; j++) {
            int chunk = tid + j * 256;
            int ci = chunk >> 4, p4 = chunk & 15;
            *(f4*)&xs[ci][p4 * 4] =
                *(const f4*)(x1 + (((size_t)b * 64 + ci) * 128 + y) * 128 + x0 + p4 * 4);
            *(f4*)&wsh[ci][p4 * 4] = *(const f4*)(wv + ci * 64 + p4 * 4);
        }
        __syncthreads();

        int c0 = (tid & 15) * 4, p0 = (tid >> 4) * 4;
        f4 bb = *(const f4*)(bv + c0);
        f4 acc[4];
        #pragma unroll
        for (int i = 0; i < 4; i++) acc[i] = bb;

        #pragma unroll
        for (int ci = 0; ci < 64; ci++) {
            f4 w4 = *(f4*)&wsh[ci][c0];
            f4 x4 = *(f4*)&xs[ci][p0];
            #pragma unroll
            for (int i = 0; i < 4; i++) acc[i] += x4[i] * w4;
        }

        #pragma unroll
        for (int i = 0; i < 4; i++) {
            int xp = x0 + p0 + i + 2;
            *(f4*)(vpad + (((size_t)b * 132 + (y + 2)) * 132 + xp) * 64 + c0) = acc[i];
        }
    }
}

// ---------------------------------------------------------------------------
// Kernel 2: conv3x3 + GELU, bf16 MFMA (R9 verbatim: 32px/2-wave/2048-block,
// swapped operands A=weights B=pixels, dwordx2 bf16 stores)
// ---------------------------------------------------------------------------
__global__ __launch_bounds__(128, 4) void conv_mfma_k(const char* __restrict__ x2tp,
                                                      const char* __restrict__ wbfT,
                                                      const float* __restrict__ bc,
                                                      char* __restrict__ featb) {
    __shared__ char slab[3 * 4352];            // 3 rows x 34 px x 128 B
    int tid = threadIdx.x;
    int l = tid & 63, w = tid >> 6;
    int bidx = xcd_swz11(blockIdx.x);          // b(2) | y(7) | xq(2)
    int xq = bidx & 3, y = (bidx >> 2) & 127, b = bidx >> 9;
    int x0 = xq << 5;

    const char* gr = x2tp + ((size_t)(b * 130 + y) * 130 + x0) * 128;
    for (int q = tid; q < 816; q += 128) {
        int r = q / 272, c = q - r * 272;
        const char* g = gr + (size_t)r * (130 * 128) + c * 16;
        char* p = slab + q * 16;
        __builtin_amdgcn_global_load_lds(
            (const __attribute__((address_space(1))) u32*)g,
            (__attribute__((address_space(3))) u32*)p, 16, 0, 0);
    }
    __syncthreads();

    int m0 = w << 4;
    int r16 = l & 15, g16 = l >> 4;
    f32x4 acc[4] = {{0.f,0.f,0.f,0.f},{0.f,0.f,0.f,0.f},
                    {0.f,0.f,0.f,0.f},{0.f,0.f,0.f,0.f}};
    const char* wb = wbfT + (size_t)r16 * 1152 + g16 * 16;

    #pragma unroll
    for (int s = 0; s < 18; s++) {
        const int t9 = s >> 1;
        const int ky = t9 / 3, kx = t9 - ky * 3;
        const int ci0g = (s & 1) * 4;
        int x_sl = m0 + r16 + kx;
        int go = (ci0g + g16) ^ (x_sl & 7);
        short8 a = *(const short8*)(slab + ky * 4352 + x_sl * 128 + go * 16);
        #pragma unroll
        for (int cb = 0; cb < 4; cb++) {
            short8 bf = *(const short8*)(wb + (size_t)cb * (16 * 1152) + s * 64);
            acc[cb] = __builtin_amdgcn_mfma_f32_16x16x32_bf16(bf, a, acc[cb], 0, 0, 0);
        }
    }

    const float kA = 0.7978845608028654f, kB = 0.044715f;
    char* fp = featb + ((size_t)b * 16384 + (size_t)y * 128 + x0 + m0 + r16) * 128;
    #pragma unroll
    for (int cb = 0; cb < 4; cb++) {
        f4 b4 = *(const f4*)(bc + cb * 16 + g16 * 4);
        u16 h[4];
        #pragma unroll
        for (int j = 0; j < 4; j++) {
            float v = acc[cb][j] + b4[j];
            float z = kA * (v + kB * v * v * v);
            float e = __expf(2.f * z);
            float th = 1.f - 2.f / (e + 1.f);
            h[j] = f2bf(0.5f * v * (1.f + th));
        }
        u32x2 pk = {(u32)h[0] | ((u32)h[1] << 16), (u32)h[2] | ((u32)h[3] << 16)};
        *(u32x2*)(fp + cb * 32 + g16 * 8) = pk;
    }
}

// ---------------------------------------------------------------------------
// Kernel 3 (v5r): dcn fused (R9 verbatim; measured 56us)
// ---------------------------------------------------------------------------
__global__ __launch_bounds__(256, 6) void dcn_fused_v5(const char* __restrict__ featb,
                                                       const float* __restrict__ vpad,
                                                       const char* __restrict__ whead,
                                                       const float* __restrict__ bo,
                                                       const float* __restrict__ bm,
                                                       const float* __restrict__ wout,
                                                       const float* __restrict__ bout,
                                                       float* __restrict__ out) {
    __shared__ float off_s [4][8][74];
    __shared__ float msk_s [4][8][38];
    __shared__ float samp_s[4][8][64];

    int tid = threadIdx.x;
    int w = tid >> 6, l = tid & 63;
    int blk = xcd_swz11(blockIdx.x);      // b(2) | y(7) | xq(2)
    int b = blk >> 9, y = (blk >> 2) & 127, xq = blk & 3;
    int x0w = xq * 32 + w * 8;
    int pix0 = ((b << 7) + y) * 128 + x0w;

    int r = l & 15, q = l >> 4;

    const char* fpt = featb + (size_t)(pix0 + (r & 7)) * 128 + q * 16;
    short8 a0 = *(const short8*)fpt;
    short8 a1 = *(const short8*)(fpt + 64);

    const char* wh = whead + (size_t)r * 128 + q * 16;
    f32x4 hc[7];
    #pragma unroll
    for (int t = 0; t < 7; t++) {
        short8 b0 = *(const short8*)(wh + t * 2048);
        short8 b1 = *(const short8*)(wh + t * 2048 + 64);
        f32x4 z = {0.f, 0.f, 0.f, 0.f};
        z = __builtin_amdgcn_mfma_f32_16x16x32_bf16(a0, b0, z, 0, 0, 0);
        hc[t] = __builtin_amdgcn_mfma_f32_16x16x32_bf16(a1, b1, z, 0, 0, 0);
    }

    if (q < 2) {
        #pragma unroll
        for (int t = 0; t < 7; t++) {
            int col = t * 16 + r;
            float bias = 0.f;
            if (col < 72)        bias = bo[col];
            else if (col < 108)  bias = bm[col - 72];
            #pragma unroll
            for (int j = 0; j < 4; j++) {
                int px = q * 4 + j;
                float v = hc[t][j] + bias;
                if (col < 72)       off_s[w][px][col] = v;
                else if (col < 108) msk_s[w][px][col - 72] = v;
            }
        }
    }

    if (l < 32) {
        int px = l >> 2, g = l & 3;
        float m[9];
        #pragma unroll
        for (int p = 0; p < 9; p++) m[p] = msk_s[w][px][g * 9 + p];
        float mx = m[0];
        #pragma unroll
        for (int p = 1; p < 9; p++) mx = fmaxf(mx, m[p]);
        float s = 0.f;
        #pragma unroll
        for (int p = 0; p < 9; p++) { m[p] = __expf(m[p] - mx); s += m[p]; }
        float inv = 1.f / s;
        #pragma unroll
        for (int p = 0; p < 9; p++) msk_s[w][px][g * 9 + p] = m[p] * inv;
    }

    {
        int cc4 = l & 3, g = (l >> 2) & 3, pxs = l >> 4;
        const float* vb = vpad + (size_t)b * 17424 * 64 + g * 16 + cc4 * 4;
        #pragma unroll
        for (int j = 0; j < 2; j++) {
            int px = pxs * 2 + j;
            int xpix = x0w + px;
            f4 acc = {0.f, 0.f, 0.f, 0.f};
            #pragma unroll
            for (int p = 0; p < 9; p++) {
                const int kx = p % 3, ky = p / 3;
                f2 oxy = *(const f2*)&off_s[w][px][g * 18 + 2 * p];
                float mv = msk_s[w][px][g * 9 + p];
                float sx = (float)(xpix + kx) + oxy[0];
                float sy = (float)(y + ky) + oxy[1];
                float xf = floorf(sx), yf = floorf(sy);
                float fx = sx - xf, fy = sy - yf;
                int ix = (int)xf, iy = (int)yf;           // in [-1,129]
                int e0 = (iy * 132 + ix + 133) << 6;
                const float* pa = vb + e0;
                f4 v00 = *(const f4*)pa;
                f4 v01 = *(const f4*)(pa + 64);
                f4 v10 = *(const f4*)(pa + 8448);
                f4 v11 = *(const f4*)(pa + 8512);
                float wy0 = mv * (1.f - fy), wy1 = mv * fy;
                float w00 = wy0 * (1.f - fx), w01 = wy0 * fx;
                float w10 = wy1 * (1.f - fx), w11 = wy1 * fx;
                #pragma unroll
                for (int c = 0; c < 4; c++)
                    acc[c] = fmaf(w00, v00[c],
                             fmaf(w01, v01[c],
                             fmaf(w10, v10[c],
                             fmaf(w11, v11[c], acc[c]))));
            }
            *(f4*)&samp_s[w][px][g * 16 + cc4 * 4] = acc;
        }
    }

    float oa[8];
    float bvv = bout[l];
    #pragma unroll
    for (int px = 0; px < 8; px++) oa[px] = bvv;
    const float* pw = wout + l;
    #pragma unroll 4
    for (int k4 = 0; k4 < 16; k4++) {
        float w0 = pw[0], w1 = pw[64], w2 = pw[128], w3 = pw[192];
        pw += 256;
        #pragma unroll
        for (int px = 0; px < 8; px++) {
            f4 sv = *(f4*)&samp_s[w][px][k4 * 4];
            oa[px] = fmaf(sv[0], w0, fmaf(sv[1], w1,
                     fmaf(sv[2], w2, fmaf(sv[3], w3, oa[px]))));
        }
    }

    float* op = out + ((size_t)b * 64 + l) * 16384 + y * 128 + x0w;
    f4 o0 = {oa[0], oa[1], oa[2], oa[3]};
    f4 o1 = {oa[4], oa[5], oa[6], oa[7]};
    *(f4*)op       = o0;
    *(f4*)(op + 4) = o1;
}

// ---------------------------------------------------------------------------
extern "C" void kernel_launch(void* const* d_in, const int* in_sizes, int n_in,
                              void* d_out, int out_size, void* d_ws, size_t ws_size,
                              hipStream_t stream) {
    const float* x1       = (const float*)d_in[0];
    const float* x2       = (const float*)d_in[1];
    const float* w_value  = (const float*)d_in[2];
    const float* b_value  = (const float*)d_in[3];
    const float* w_conv   = (const float*)d_in[4];
    const float* b_conv   = (const float*)d_in[5];
    const float* w_offset = (const float*)d_in[6];
    const float* b_offset = (const float*)d_in[7];
    const float* w_mask   = (const float*)d_in[8];
    const float* b_mask   = (const float*)d_in[9];
    const float* w_out    = (const float*)d_in[10];
    const float* b_out    = (const float*)d_in[11];

    float* vpad  = (float*)d_ws;
    char*  featb = (char*)d_ws + 17842176;
    char*  x2tp  = (char*)d_ws + 26230784;
    char*  wbfT  = (char*)d_ws + 34883584;
    char*  whead = (char*)d_ws + 34957312;
    float* outp  = (float*)d_out;

    hipLaunchKernelGGL(mega_prep_k,  dim3(1961), dim3(256), 0, stream,
                       vpad, x2tp, w_conv, w_offset, w_mask, wbfT, whead,
                       x2, x1, w_value, b_value);
    hipLaunchKernelGGL(conv_mfma_k,  dim3(2048), dim3(128), 0, stream,
                       x2tp, wbfT, b_conv, featb);
    hipLaunchKernelGGL(dcn_fused_v5, dim3(2048), dim3(256), 0, stream,
                       featb, vpad, whead, b_offset, b_mask, w_out, b_out, outp);
}

// Round 12
// 185.839 us; speedup vs baseline: 1.0879x; 1.0340x over previous
//
#include <hip/hip_runtime.h>
#include <cstdint>
#include <cstddef>

typedef float f4 __attribute__((ext_vector_type(4)));
typedef float f2 __attribute__((ext_vector_type(2)));
typedef float f32x4 __attribute__((ext_vector_type(4)));
typedef short short8 __attribute__((ext_vector_type(8)));
typedef unsigned int u32;
typedef unsigned short u16;
typedef u32 u32x2 __attribute__((ext_vector_type(2)));
typedef u32 u32x4 __attribute__((ext_vector_type(4)));

// Problem: B=4, H=W=128, CH=64 (G=4 x GC=16), K=3, PAD=1, P=9
// ws layout:
//   vpad  fp32 [4][132][132][64] (2-ring zero) @ 0          17,842,176 B
//   x2tp  bf16 [4][130][130][64] swizzled      @ 17,842,176  8,652,800 B
//   wbfT  bf16 [64][576]                       @ 26,494,976     73,728 B
//   whead bf16 [112 cols][64 k]                @ 26,568,704     14,336 B
// Pipeline: 2 launches. mega_prep (R11 verbatim) -> conv+dcn fused
// (featb buffer eliminated; conv output handed off through LDS).

__device__ __forceinline__ u16 f2bf(float f) {
    u32 u = __builtin_bit_cast(u32, f);
    return (u16)((u + 0x7FFFu + ((u >> 16) & 1u)) >> 16);
}

__device__ __forceinline__ int xcd_swz10(int d) {   // 1024 blocks
    return ((d & 7) << 7) | (d >> 3);
}
__device__ __forceinline__ int xcd_swz11(int d) {   // 2048 blocks
    return ((d & 7) << 8) | (d >> 3);
}

// ---------------------------------------------------------------------------
// Kernel 1 (mega, R11 verbatim): [0,425) preps | [425,937) x2prep |
// [937,1961) value_proj
// ---------------------------------------------------------------------------
__global__ __launch_bounds__(256, 4) void mega_prep_k(float* __restrict__ vpad,
                                                      char* __restrict__ x2tp,
                                                      const float* __restrict__ wc,
                                                      const float* __restrict__ wo,
                                                      const float* __restrict__ wm,
                                                      char* __restrict__ wbfT,
                                                      char* __restrict__ whead,
                                                      const float* __restrict__ x2,
                                                      const float* __restrict__ x1,
                                                      const float* __restrict__ wv,
                                                      const float* __restrict__ bv) {
    __shared__ __align__(16) char smem[32768];
    int blk = blockIdx.x;

    if (blk < 425) {
        if (blk < 260) {
            int i = blk * 256 + threadIdx.x;
            if (i >= 66560) return;
            int c4 = i & 15;
            int rest = i >> 4;
            int b = rest / 1040;
            int e = rest - b * 1040;
            int y, x;
            if (e < 132)      { y = 0;   x = e; }
            else if (e < 264) { y = 1;   x = e - 132; }
            else if (e < 396) { y = 130; x = e - 264; }
            else if (e < 528) { y = 131; x = e - 396; }
            else { int e2 = e - 528; y = 2 + (e2 >> 2); int m = e2 & 3;
                   x = (m < 2) ? m : m + 128; }
            f4 z = {0.f, 0.f, 0.f, 0.f};
            *(f4*)(vpad + (((size_t)b * 17424 + (size_t)y * 132 + x) * 64 + c4 * 4)) = z;
        } else if (blk < 325) {
            int i = (blk - 260) * 256 + threadIdx.x;
            if (i >= 16512) return;
            int c8 = i & 7;
            int rest = i >> 3;
            int b = rest / 516;
            int e = rest - b * 516;
            int y, x;
            if (e < 130)      { y = 0;       x = e; }
            else if (e < 260) { y = 129;     x = e - 130; }
            else if (e < 388) { y = e - 259; x = 0; }
            else              { y = e - 387; x = 129; }
            u32x4 z = {0u, 0u, 0u, 0u};
            *(u32x4*)(x2tp + ((size_t)b * 16900 + (size_t)y * 130 + x) * 128 + c8 * 16) = z;
        } else if (blk < 397) {
            int i = (blk - 325) * 256 + threadIdx.x;
            int c = i / 288, kp = i - c * 288;
            int k = kp << 1;
            float f0 = wc[(size_t)k * 64 + c];
            float f1 = wc[(size_t)(k + 1) * 64 + c];
            u32 pk = (u32)f2bf(f0) | ((u32)f2bf(f1) << 16);
            *(u32*)(wbfT + (size_t)c * 1152 + kp * 4) = pk;
        } else {
            int i = (blk - 397) * 256 + threadIdx.x;
            int k = i & 63, col = i >> 6;
            float v = 0.f;
            if (col < 72)       v = wo[(size_t)k * 72 + col];
            else if (col < 108) v = wm[(size_t)k * 36 + col - 72];
            *(u16*)(whead + (size_t)(col * 64 + k) * 2) = f2bf(v);
        }
    } else if (blk < 937) {
        u32* tr = (u32*)smem;
        int local = blk - 425;
        int t = threadIdx.x;
        int y = local & 127, b = local >> 7;
        const float* xb = x2 + (size_t)b * 64 * 16384 + (size_t)y * 128;
        #pragma unroll 4
        for (int j = 0; j < 16; j++) {
            int idx = t + (j << 8);
            int x = idx & 127, cip = idx >> 7;
            int ci = cip << 1;
            float f0 = xb[(size_t)ci * 16384 + x];
            float f1 = xb[(size_t)(ci + 1) * 16384 + x];
            u32 pk = (u32)f2bf(f0) | ((u32)f2bf(f1) << 16);
            int key = (x + 1) & 7;
            int byt = x * 128 + (((ci >> 3) ^ key) << 4) + (ci & 7) * 2;
            tr[byt >> 2] = pk;
        }
        __syncthreads();
        const u32x4* src = (const u32x4*)tr;
        u32x4* dst = (u32x4*)(x2tp + ((size_t)(b * 130 + y + 1) * 130 + 1) * 128);
        #pragma unroll
        for (int j = 0; j < 4; j++) {
            int c = t + (j << 8);
            dst[c] = src[c];
        }
    } else {
        float (*xs)[64]  = (float(*)[64])smem;
        float (*wsh)[64] = (float(*)[64])(smem + 16384);
        int tid = threadIdx.x;
        int bidx = xcd_swz10(blk - 937);
        int xb = bidx & 1;
        int y  = (bidx >> 1) & 127;
        int b  = bidx >> 8;
        int x0 = xb * 64;

        #pragma unroll
        for (int j = 0; j < 4; j++) {
            int chunk = tid + j * 256;
            int ci = chunk >> 4, p4 = chunk & 15;
            *(f4*)&xs[ci][p4 * 4] =
                *(const f4*)(x1 + (((size_t)b * 64 + ci) * 128 + y) * 128 + x0 + p4 * 4);
            *(f4*)&wsh[ci][p4 * 4] = *(const f4*)(wv + ci * 64 + p4 * 4);
        }
        __syncthreads();

        int c0 = (tid & 15) * 4, p0 = (tid >> 4) * 4;
        f4 bb = *(const f4*)(bv + c0);
        f4 acc[4];
        #pragma unroll
        for (int i = 0; i < 4; i++) acc[i] = bb;

        #pragma unroll
        for (int ci = 0; ci < 64; ci++) {
            f4 w4 = *(f4*)&wsh[ci][c0];
            f4 x4 = *(f4*)&xs[ci][p0];
            #pragma unroll
            for (int i = 0; i < 4; i++) acc[i] += x4[i] * w4;
        }

        #pragma unroll
        for (int i = 0; i < 4; i++) {
            int xp = x0 + p0 + i + 2;
            *(f4*)(vpad + (((size_t)b * 132 + (y + 2)) * 132 + xp) * 64 + c0) = acc[i];
        }
    }
}

// ---------------------------------------------------------------------------
// Kernel 2: conv3x3+GELU fused with dcn. 2048 blocks (b(2)|y(7)|xq(2)),
// 256 thr / 4 waves, same decode both phases.
//   Phase 1: stage x2tp slab (R9 conv verbatim) -> conv MFMA, 4-way wave
//            split (wave w: px-half w&1, ch-blocks (w>>1)*2..+1) -> GELU ->
//            feat to LDS (bf16, R9 epilogue pattern).
//   Phase 2: dcn_v5 verbatim, A-frags from feat LDS (featb eliminated).
// LDS union (26,624 B): [slab 13056 | off 9472 + msk 4864] + feat 4096 +
// samp 8192. off/msk overlay the dead slab; samp kept disjoint from feat
// (cross-wave feat reads must not race samp writes).
// ---------------------------------------------------------------------------
__global__ __launch_bounds__(256, 6) void conv_dcn_k(const char* __restrict__ x2tp,
                                                     const char* __restrict__ wbfT,
                                                     const float* __restrict__ bc,
                                                     const float* __restrict__ vpad,
                                                     const char* __restrict__ whead,
                                                     const float* __restrict__ bo,
                                                     const float* __restrict__ bm,
                                                     const float* __restrict__ wout,
                                                     const float* __restrict__ bout,
                                                     float* __restrict__ out) {
    __shared__ __align__(16) char smem[26624];
    char*  slab  = smem;                         // [0, 13056)   phase 1
    float* off_s = (float*)smem;                 // [0, 9472)    phase 2
    float* msk_s = (float*)(smem + 9472);        // [9472,14336) phase 2
    char*  featl = smem + 14336;                 // [14336,18432) conv->heads
    float* samp_s= (float*)(smem + 18432);       // [18432,26624) sampling->proj

    int tid = threadIdx.x;
    int l = tid & 63, w = tid >> 6;
    int blk = xcd_swz11(blockIdx.x);             // b(2) | y(7) | xq(2)
    int b = blk >> 9, y = (blk >> 2) & 127, xq = blk & 3;
    int x0 = xq << 5;
    int r16 = l & 15, g16 = l >> 4;

    // ===== Phase 1a: stage slab (3 rows x 34 px x 128 B) =====
    const char* gr = x2tp + ((size_t)(b * 130 + y) * 130 + x0) * 128;
    for (int q = tid; q < 816; q += 256) {
        int rr = q / 272, c = q - rr * 272;
        const char* g = gr + (size_t)rr * (130 * 128) + c * 16;
        char* p = slab + q * 16;
        __builtin_amdgcn_global_load_lds(
            (const __attribute__((address_space(1))) u32*)g,
            (__attribute__((address_space(3))) u32*)p, 16, 0, 0);
    }
    __syncthreads();

    // ===== Phase 1b: conv MFMA (swapped: A=weights, B=pixels) =====
    {
        int m0c = (w & 1) << 4;                  // px half: 0 / 16
        int cbb = (w >> 1) << 1;                 // ch blocks: 0-1 / 2-3
        f32x4 acc[2] = {{0.f,0.f,0.f,0.f},{0.f,0.f,0.f,0.f}};
        const char* wb = wbfT + (size_t)r16 * 1152 + g16 * 16;

        #pragma unroll
        for (int s = 0; s < 18; s++) {
            const int t9 = s >> 1;
            const int ky = t9 / 3, kx = t9 - ky * 3;
            const int ci0g = (s & 1) * 4;
            int x_sl = m0c + r16 + kx;           // 0..33; x0%8==0 -> key=x_sl&7
            int go = (ci0g + g16) ^ (x_sl & 7);
            short8 a = *(const short8*)(slab + ky * 4352 + x_sl * 128 + go * 16);
            #pragma unroll
            for (int c2 = 0; c2 < 2; c2++) {
                short8 bf = *(const short8*)(wb + (size_t)(cbb + c2) * 18432 + s * 64);
                acc[c2] = __builtin_amdgcn_mfma_f32_16x16x32_bf16(bf, a, acc[c2], 0, 0, 0);
            }
        }

        // GELU + feat -> LDS (lane: px = m0c+r16, ch = (cbb+c2)*16 + g16*4 + j)
        const float kA = 0.7978845608028654f, kB = 0.044715f;
        char* fp = featl + (size_t)(m0c + r16) * 128;
        #pragma unroll
        for (int c2 = 0; c2 < 2; c2++) {
            int cb = cbb + c2;
            f4 b4 = *(const f4*)(bc + cb * 16 + g16 * 4);
            u16 h[4];
            #pragma unroll
            for (int j = 0; j < 4; j++) {
                float v = acc[c2][j] + b4[j];
                float z = kA * (v + kB * v * v * v);
                float e = __expf(2.f * z);
                float th = 1.f - 2.f / (e + 1.f);
                h[j] = f2bf(0.5f * v * (1.f + th));
            }
            u32x2 pk = {(u32)h[0] | ((u32)h[1] << 16), (u32)h[2] | ((u32)h[3] << 16)};
            *(u32x2*)(fp + cb * 32 + g16 * 8) = pk;
        }
    }
    __syncthreads();                             // feat ready; slab dead

    // ===== Phase 2: dcn (R9 verbatim, A-frags from feat LDS) =====
    int x0w = x0 + w * 8;
    int r = r16, q = g16;

    const char* fpt = featl + (size_t)(w * 8 + (r & 7)) * 128 + q * 16;
    short8 a0 = *(const short8*)fpt;
    short8 a1 = *(const short8*)(fpt + 64);

    const char* wh = whead + (size_t)r * 128 + q * 16;
    f32x4 hc[7];
    #pragma unroll
    for (int t = 0; t < 7; t++) {
        short8 b0 = *(const short8*)(wh + t * 2048);
        short8 b1 = *(const short8*)(wh + t * 2048 + 64);
        f32x4 z = {0.f, 0.f, 0.f, 0.f};
        z = __builtin_amdgcn_mfma_f32_16x16x32_bf16(a0, b0, z, 0, 0, 0);
        hc[t] = __builtin_amdgcn_mfma_f32_16x16x32_bf16(a1, b1, z, 0, 0, 0);
    }

    if (q < 2) {
        #pragma unroll
        for (int t = 0; t < 7; t++) {
            int col = t * 16 + r;
            float bias = 0.f;
            if (col < 72)        bias = bo[col];
            else if (col < 108)  bias = bm[col - 72];
            #pragma unroll
            for (int j = 0; j < 4; j++) {
                int px = q * 4 + j;
                float v = hc[t][j] + bias;
                if (col < 72)       off_s[(w * 8 + px) * 74 + col] = v;
                else if (col < 108) msk_s[(w * 8 + px) * 38 + (col - 72)] = v;
            }
        }
    }

    if (l < 32) {
        int px = l >> 2, g = l & 3;
        float* m9 = &msk_s[(w * 8 + px) * 38 + g * 9];
        float m[9];
        #pragma unroll
        for (int p = 0; p < 9; p++) m[p] = m9[p];
        float mx = m[0];
        #pragma unroll
        for (int p = 1; p < 9; p++) mx = fmaxf(mx, m[p]);
        float s = 0.f;
        #pragma unroll
        for (int p = 0; p < 9; p++) { m[p] = __expf(m[p] - mx); s += m[p]; }
        float inv = 1.f / s;
        #pragma unroll
        for (int p = 0; p < 9; p++) m9[p] = m[p] * inv;
    }

    {
        int cc4 = l & 3, g = (l >> 2) & 3, pxs = l >> 4;
        const float* vb = vpad + (size_t)b * 17424 * 64 + g * 16 + cc4 * 4;
        #pragma unroll
        for (int j = 0; j < 2; j++) {
            int px = pxs * 2 + j;
            int xpix = x0w + px;
            const float* offp = &off_s[(w * 8 + px) * 74 + g * 18];
            const float* mskp = &msk_s[(w * 8 + px) * 38 + g * 9];
            f4 acc = {0.f, 0.f, 0.f, 0.f};
            #pragma unroll
            for (int p = 0; p < 9; p++) {
                const int kx = p % 3, ky = p / 3;
                f2 oxy = *(const f2*)&offp[2 * p];
                float mv = mskp[p];
                float sx = (float)(xpix + kx) + oxy[0];
                float sy = (float)(y + ky) + oxy[1];
                float xf = floorf(sx), yf = floorf(sy);
                float fx = sx - xf, fy = sy - yf;
                int ix = (int)xf, iy = (int)yf;           // in [-1,129]
                int e0 = (iy * 132 + ix + 133) << 6;
                const float* pa = vb + e0;
                f4 v00 = *(const f4*)pa;
                f4 v01 = *(const f4*)(pa + 64);
                f4 v10 = *(const f4*)(pa + 8448);
                f4 v11 = *(const f4*)(pa + 8512);
                float wy0 = mv * (1.f - fy), wy1 = mv * fy;
                float w00 = wy0 * (1.f - fx), w01 = wy0 * fx;
                float w10 = wy1 * (1.f - fx), w11 = wy1 * fx;
                #pragma unroll
                for (int c = 0; c < 4; c++)
                    acc[c] = fmaf(w00, v00[c],
                             fmaf(w01, v01[c],
                             fmaf(w10, v10[c],
                             fmaf(w11, v11[c], acc[c]))));
            }
            *(f4*)&samp_s[(w * 8 + px) * 64 + g * 16 + cc4 * 4] = acc;
        }
    }

    float oa[8];
    float bvv = bout[l];
    #pragma unroll
    for (int px = 0; px < 8; px++) oa[px] = bvv;
    const float* pw = wout + l;
    #pragma unroll 4
    for (int k4 = 0; k4 < 16; k4++) {
        float w0 = pw[0], w1 = pw[64], w2 = pw[128], w3 = pw[192];
        pw += 256;
        #pragma unroll
        for (int px = 0; px < 8; px++) {
            f4 sv = *(f4*)&samp_s[(w * 8 + px) * 64 + k4 * 4];
            oa[px] = fmaf(sv[0], w0, fmaf(sv[1], w1,
                     fmaf(sv[2], w2, fmaf(sv[3], w3, oa[px]))));
        }
    }

    float* op = out + ((size_t)b * 64 + l) * 16384 + y * 128 + x0w;
    f4 o0 = {oa[0], oa[1], oa[2], oa[3]};
    f4 o1 = {oa[4], oa[5], oa[6], oa[7]};
    *(f4*)op       = o0;
    *(f4*)(op + 4) = o1;
}

// ---------------------------------------------------------------------------
extern "C" void kernel_launch(void* const* d_in, const int* in_sizes, int n_in,
                              void* d_out, int out_size, void* d_ws, size_t ws_size,
                              hipStream_t stream) {
    const float* x1       = (const float*)d_in[0];
    const float* x2       = (const float*)d_in[1];
    const float* w_value  = (const float*)d_in[2];
    const float* b_value  = (const float*)d_in[3];
    const float* w_conv   = (const float*)d_in[4];
    const float* b_conv   = (const float*)d_in[5];
    const float* w_offset = (const float*)d_in[6];
    const float* b_offset = (const float*)d_in[7];
    const float* w_mask   = (const float*)d_in[8];
    const float* b_mask   = (const float*)d_in[9];
    const float* w_out    = (const float*)d_in[10];
    const float* b_out    = (const float*)d_in[11];

    float* vpad  = (float*)d_ws;
    char*  x2tp  = (char*)d_ws + 17842176;
    char*  wbfT  = (char*)d_ws + 26494976;
    char*  whead = (char*)d_ws + 26568704;
    float* outp  = (float*)d_out;

    hipLaunchKernelGGL(mega_prep_k, dim3(1961), dim3(256), 0, stream,
                       vpad, x2tp, w_conv, w_offset, w_mask, wbfT, whead,
                       x2, x1, w_value, b_value);
    hipLaunchKernelGGL(conv_dcn_k,  dim3(2048), dim3(256), 0, stream,
                       x2tp, wbfT, b_conv, vpad, whead,
                       b_offset, b_mask, w_out, b_out, outp);
}